// Round 5
// baseline (498.431 us; speedup 1.0000x reference)
//
#include <hip/hip_runtime.h>
#include <math.h>

#define NHID 64
#define NPB 256          // nodes per bucket (power of two; local id = node & 255)
#define NPB_SHIFT 8
#define MAXB 512         // supports N up to 131072
#define CAP 10240        // entries per bucket region (mean 8184 @ E=3.2M, +23 sigma)
#define CHUNK 8192       // edges per k_bucketA block

// ---------------------------------------------------------------------------
// K_A: two-level bucketing of both endpoints. One block per 8192-edge chunk.
// LDS histogram over coarse buckets -> ONE global atomic per (block,bucket)
// reserves a contiguous slice -> LDS-rank scatter of packed (payload<<8|local)
// entries. Global atomics: ~300K total.
// ---------------------------------------------------------------------------
__global__ __launch_bounds__(256) void k_bucketA(const int* __restrict__ src,
                                                 const int* __restrict__ dst,
                                                 unsigned int* __restrict__ buf0,  // keyed by dst, payload src
                                                 unsigned int* __restrict__ buf1,  // keyed by src, payload dst
                                                 int* __restrict__ btail0,
                                                 int* __restrict__ btail1,
                                                 int E, int nB) {
    __shared__ int h0[MAXB], h1[MAXB], b0[MAXB], b1[MAXB];
    int tid = threadIdx.x;
    for (int i = tid; i < nB; i += 256) { h0[i] = 0; h1[i] = 0; }
    __syncthreads();
    int e0 = blockIdx.x * CHUNK;
    for (int i = tid; i < CHUNK; i += 256) {
        int e = e0 + i;
        if (e < E) {
            atomicAdd(&h0[dst[e] >> NPB_SHIFT], 1);
            atomicAdd(&h1[src[e] >> NPB_SHIFT], 1);
        }
    }
    __syncthreads();
    for (int i = tid; i < nB; i += 256) {
        int c0 = h0[i], c1 = h1[i];
        b0[i] = c0 ? atomicAdd(&btail0[i], c0) : 0;
        b1[i] = c1 ? atomicAdd(&btail1[i], c1) : 0;
        h0[i] = 0; h1[i] = 0;       // reuse as rank counters
    }
    __syncthreads();
    for (int i = tid; i < CHUNK; i += 256) {
        int e = e0 + i;
        if (e < E) {
            int d = dst[e], s = src[e];
            int bb = d >> NPB_SHIFT;
            int r = atomicAdd(&h0[bb], 1) + b0[bb];
            if (r < CAP)
                buf0[(size_t)bb * CAP + r] = ((unsigned)s << NPB_SHIFT) | (unsigned)(d & (NPB - 1));
            bb = s >> NPB_SHIFT;
            r = atomicAdd(&h1[bb], 1) + b1[bb];
            if (r < CAP)
                buf1[(size_t)bb * CAP + r] = ((unsigned)d << NPB_SHIFT) | (unsigned)(s & (NPB - 1));
        }
    }
}

// ---------------------------------------------------------------------------
// K_B: single-block exclusive scan of per-bucket sizes (both sides).
// ---------------------------------------------------------------------------
__global__ __launch_bounds__(512) void k_bscan(const int* __restrict__ btail0,
                                               const int* __restrict__ btail1,
                                               int* __restrict__ boff0, int* __restrict__ boff1,
                                               int* __restrict__ off0, int* __restrict__ off1,
                                               int nB, int N) {
    __shared__ int sd[512];
    int tid = threadIdx.x;
    int v = (tid < nB) ? min(btail0[tid], CAP) : 0;
    sd[tid] = v; __syncthreads();
    for (int o = 1; o < 512; o <<= 1) {
        int t = (tid >= o) ? sd[tid - o] : 0; __syncthreads();
        sd[tid] += t; __syncthreads();
    }
    if (tid < nB) boff0[tid] = sd[tid] - v;
    if (tid == 511) off0[N] = sd[511];
    __syncthreads();
    v = (tid < nB) ? min(btail1[tid], CAP) : 0;
    sd[tid] = v; __syncthreads();
    for (int o = 1; o < 512; o <<= 1) {
        int t = (tid >= o) ? sd[tid - o] : 0; __syncthreads();
        sd[tid] += t; __syncthreads();
    }
    if (tid < nB) boff1[tid] = sd[tid] - v;
    if (tid == 511) off1[N] = sd[511];
}

// ---------------------------------------------------------------------------
// K_C: per (side,bucket) workgroup: LDS count -> LDS scan -> emit off[] ->
// LDS-atomic rank scatter into the bucket's csr window. Zero global atomics.
// ---------------------------------------------------------------------------
__global__ __launch_bounds__(256) void k_bucket_csr(const unsigned int* __restrict__ buf0,
                                                    const unsigned int* __restrict__ buf1,
                                                    const int* __restrict__ btail0,
                                                    const int* __restrict__ btail1,
                                                    const int* __restrict__ boff0,
                                                    const int* __restrict__ boff1,
                                                    int* __restrict__ off0, int* __restrict__ off1,
                                                    int* __restrict__ csr0, int* __restrict__ csr1,
                                                    int N) {
    int side = blockIdx.x & 1;
    int b = blockIdx.x >> 1;
    const unsigned int* buf = (side ? buf1 : buf0) + (size_t)b * CAP;
    int cnt_b = min((side ? btail1 : btail0)[b], CAP);
    int boff  = (side ? boff1 : boff0)[b];
    int* off  = side ? off1 : off0;
    int* csr  = side ? csr1 : csr0;
    __shared__ int cnt[NPB];
    __shared__ int scn[NPB];
    __shared__ int cur[NPB];
    int tid = threadIdx.x;          // blockDim == NPB == 256
    cnt[tid] = 0;
    __syncthreads();
    for (int i = tid; i < cnt_b; i += 256)
        atomicAdd(&cnt[buf[i] & (NPB - 1)], 1);
    __syncthreads();
    int v = cnt[tid];
    scn[tid] = v; __syncthreads();
    for (int o = 1; o < 256; o <<= 1) {
        int t = (tid >= o) ? scn[tid - o] : 0; __syncthreads();
        scn[tid] += t; __syncthreads();
    }
    int base = boff + scn[tid] - v;   // exclusive
    cur[tid] = base;
    int node = (b << NPB_SHIFT) + tid;
    if (node < N) off[node] = base;
    __syncthreads();
    for (int i = tid; i < cnt_b; i += 256) {
        unsigned int u = buf[i];
        int pos = atomicAdd(&cur[u & (NPB - 1)], 1);
        csr[pos] = (int)(u >> NPB_SHIFT);
    }
}

// ---------------------------------------------------------------------------
// K4: agg[n,:] = mean over in-edges of X[src,:].
// Wave = 4 row-groups x 16 float4-columns; 4 dwordx4 loads (16 edges) in
// flight per wave for MLP. Tail slots masked by 0/1 multiplier.
// ---------------------------------------------------------------------------
__global__ __launch_bounds__(256) void k_agg(const float* __restrict__ X,
                                             const int* __restrict__ off_dst,
                                             const int* __restrict__ csr_dst,
                                             float* __restrict__ agg, int N) {
    int lane = threadIdx.x & 63;
    int node = blockIdx.x * 4 + (threadIdx.x >> 6);
    if (node >= N) return;
    int grp = lane >> 4, col = lane & 15;
    const float4* Xv = (const float4*)X;
    int s0 = off_dst[node], s1 = off_dst[node + 1];
    float4 acc = make_float4(0.f, 0.f, 0.f, 0.f);
    for (int base = s0; base < s1; base += 64) {
        int cnt = min(64, s1 - base);
        int idx = (base + lane < s1) ? csr_dst[base + lane] : 0;
        for (int j = 0; j < cnt; j += 16) {
            int q0 = j + grp, q1 = j + 4 + grp, q2 = j + 8 + grp, q3 = j + 12 + grp;
            int m0 = __shfl(idx, q0);
            int m1 = __shfl(idx, q1);
            int m2 = __shfl(idx, q2);
            int m3 = __shfl(idx, q3);
            float f0 = (q0 < cnt) ? 1.f : 0.f; if (q0 >= cnt) m0 = 0;
            float f1 = (q1 < cnt) ? 1.f : 0.f; if (q1 >= cnt) m1 = 0;
            float f2 = (q2 < cnt) ? 1.f : 0.f; if (q2 >= cnt) m2 = 0;
            float f3 = (q3 < cnt) ? 1.f : 0.f; if (q3 >= cnt) m3 = 0;
            float4 x0 = Xv[(size_t)m0 * 16 + col];
            float4 x1 = Xv[(size_t)m1 * 16 + col];
            float4 x2 = Xv[(size_t)m2 * 16 + col];
            float4 x3 = Xv[(size_t)m3 * 16 + col];
            acc.x += f0 * x0.x; acc.y += f0 * x0.y; acc.z += f0 * x0.z; acc.w += f0 * x0.w;
            acc.x += f1 * x1.x; acc.y += f1 * x1.y; acc.z += f1 * x1.z; acc.w += f1 * x1.w;
            acc.x += f2 * x2.x; acc.y += f2 * x2.y; acc.z += f2 * x2.z; acc.w += f2 * x2.w;
            acc.x += f3 * x3.x; acc.y += f3 * x3.y; acc.z += f3 * x3.z; acc.w += f3 * x3.w;
        }
    }
    acc.x += __shfl_xor(acc.x, 16); acc.y += __shfl_xor(acc.y, 16);
    acc.z += __shfl_xor(acc.z, 16); acc.w += __shfl_xor(acc.w, 16);
    acc.x += __shfl_xor(acc.x, 32); acc.y += __shfl_xor(acc.y, 32);
    acc.z += __shfl_xor(acc.z, 32); acc.w += __shfl_xor(acc.w, 32);
    if (grp == 0) {
        int deg = s1 - s0;
        float inv = 1.f / (float)max(deg, 1);
        float4 r = make_float4(acc.x * inv, acc.y * inv, acc.z * inv, acc.w * inv);
        ((float4*)agg)[(size_t)node * 16 + col] = r;
    }
}

// ---------------------------------------------------------------------------
// K5a: X2 = relu(X·Wself + agg·Wneigh + b), thread-per-node GEMV.
// __launch_bounds__(256,1): allow ~130 VGPRs so acc[64] stays in registers
// (round-4 profile: VGPR=44 + 64MB scratch writes = spilled accumulators).
// #pragma unroll 2 keeps the unroller from inflating live ranges.
// Writes in-place over agg.
// ---------------------------------------------------------------------------
__global__ __launch_bounds__(256, 1) void k_phaseA(const float* __restrict__ X,
                                                   const float* __restrict__ agg,
                                                   const float* __restrict__ Ws,
                                                   const float* __restrict__ Wn,
                                                   const float* __restrict__ bconv,
                                                   float* __restrict__ X2, int N) {
    int n = blockIdx.x * blockDim.x + threadIdx.x;
    if (n >= N) return;
    float acc[NHID];
    #pragma unroll
    for (int c = 0; c < NHID; ++c) acc[c] = bconv[c];
    const float4* Xv = (const float4*)(X + (size_t)n * NHID);
    const float4* Gv = (const float4*)(agg + (size_t)n * NHID);
    auto step = [&](float xs, float gs, int k) {
        #pragma unroll
        for (int c = 0; c < NHID; ++c)
            acc[c] += xs * Ws[k * NHID + c] + gs * Wn[k * NHID + c];
    };
    #pragma unroll 2
    for (int q = 0; q < 16; ++q) {
        float4 xq = Xv[q];
        float4 gq = Gv[q];
        step(xq.x, gq.x, 4 * q + 0);
        step(xq.y, gq.y, 4 * q + 1);
        step(xq.z, gq.z, 4 * q + 2);
        step(xq.w, gq.w, 4 * q + 3);
    }
    float4* out = (float4*)(X2 + (size_t)n * NHID);
    #pragma unroll
    for (int c = 0; c < NHID; c += 4)
        out[c >> 2] = make_float4(fmaxf(acc[c], 0.f), fmaxf(acc[c + 1], 0.f),
                                  fmaxf(acc[c + 2], 0.f), fmaxf(acc[c + 3], 0.f));
}

// ---------------------------------------------------------------------------
// K5b: a = X2·A + Qb ; b = X2·B (A/B = top/bottom halves of Qw).
// Same anti-spill treatment as K5a.
// ---------------------------------------------------------------------------
__global__ __launch_bounds__(256, 1) void k_phaseB(const float* __restrict__ X2,
                                                   const float* __restrict__ Qw,
                                                   const float* __restrict__ Qb,
                                                   float* __restrict__ aOut,
                                                   float* __restrict__ bOut, int N) {
    int n = blockIdx.x * blockDim.x + threadIdx.x;
    if (n >= N) return;
    const float4* Xv = (const float4*)(X2 + (size_t)n * NHID);
    float acc[NHID];

    // pass 1: a = X2·A + Qb   (A[f][c] = Qw[(c>>4)*2048 + f*16 + (c&15)])
    #pragma unroll
    for (int c = 0; c < NHID; ++c) acc[c] = Qb[c];
    auto stepA = [&](float xs, int f) {
        #pragma unroll
        for (int c = 0; c < NHID; ++c)
            acc[c] += xs * Qw[(c >> 4) * 2048 + f * 16 + (c & 15)];
    };
    #pragma unroll 2
    for (int q = 0; q < 16; ++q) {
        float4 xq = Xv[q];
        stepA(xq.x, 4 * q + 0);
        stepA(xq.y, 4 * q + 1);
        stepA(xq.z, 4 * q + 2);
        stepA(xq.w, 4 * q + 3);
    }
    float4* oa = (float4*)(aOut + (size_t)n * NHID);
    #pragma unroll
    for (int c = 0; c < NHID; c += 4)
        oa[c >> 2] = make_float4(acc[c], acc[c + 1], acc[c + 2], acc[c + 3]);

    // pass 2: b = X2·B
    #pragma unroll
    for (int c = 0; c < NHID; ++c) acc[c] = 0.f;
    auto stepB = [&](float xs, int f) {
        #pragma unroll
        for (int c = 0; c < NHID; ++c)
            acc[c] += xs * Qw[(c >> 4) * 2048 + (64 + f) * 16 + (c & 15)];
    };
    #pragma unroll 2
    for (int q = 0; q < 16; ++q) {
        float4 xq = Xv[q];
        stepB(xq.x, 4 * q + 0);
        stepB(xq.y, 4 * q + 1);
        stepB(xq.z, 4 * q + 2);
        stepB(xq.w, 4 * q + 3);
    }
    float4* ob = (float4*)(bOut + (size_t)n * NHID);
    #pragma unroll
    for (int c = 0; c < NHID; c += 4)
        ob[c >> 2] = make_float4(acc[c], acc[c + 1], acc[c + 2], acc[c + 3]);
}

// ---------------------------------------------------------------------------
// K6: gg[n,:] = tanh(mean over out-edges of (a[n,:] + b[dst,:])^2)
// Same 16-edges-in-flight structure as K4.
// ---------------------------------------------------------------------------
__global__ __launch_bounds__(256) void k_final(const float* __restrict__ aF,
                                               const float* __restrict__ bF,
                                               const int* __restrict__ off_src,
                                               const int* __restrict__ csr_src,
                                               float* __restrict__ out, int N) {
    int lane = threadIdx.x & 63;
    int node = blockIdx.x * 4 + (threadIdx.x >> 6);
    if (node >= N) return;
    int grp = lane >> 4, col = lane & 15;
    const float4* Bv = (const float4*)bF;
    float4 av = ((const float4*)aF)[(size_t)node * 16 + col];
    int s0 = off_src[node], s1 = off_src[node + 1];
    float4 acc = make_float4(0.f, 0.f, 0.f, 0.f);
    for (int base = s0; base < s1; base += 64) {
        int cnt = min(64, s1 - base);
        int idx = (base + lane < s1) ? csr_src[base + lane] : 0;
        for (int j = 0; j < cnt; j += 16) {
            int q0 = j + grp, q1 = j + 4 + grp, q2 = j + 8 + grp, q3 = j + 12 + grp;
            int m0 = __shfl(idx, q0);
            int m1 = __shfl(idx, q1);
            int m2 = __shfl(idx, q2);
            int m3 = __shfl(idx, q3);
            float f0 = (q0 < cnt) ? 1.f : 0.f; if (q0 >= cnt) m0 = 0;
            float f1 = (q1 < cnt) ? 1.f : 0.f; if (q1 >= cnt) m1 = 0;
            float f2 = (q2 < cnt) ? 1.f : 0.f; if (q2 >= cnt) m2 = 0;
            float f3 = (q3 < cnt) ? 1.f : 0.f; if (q3 >= cnt) m3 = 0;
            float4 b0 = Bv[(size_t)m0 * 16 + col];
            float4 b1 = Bv[(size_t)m1 * 16 + col];
            float4 b2 = Bv[(size_t)m2 * 16 + col];
            float4 b3 = Bv[(size_t)m3 * 16 + col];
            float t;
            t = av.x + b0.x; acc.x += f0 * t * t;
            t = av.y + b0.y; acc.y += f0 * t * t;
            t = av.z + b0.z; acc.z += f0 * t * t;
            t = av.w + b0.w; acc.w += f0 * t * t;
            t = av.x + b1.x; acc.x += f1 * t * t;
            t = av.y + b1.y; acc.y += f1 * t * t;
            t = av.z + b1.z; acc.z += f1 * t * t;
            t = av.w + b1.w; acc.w += f1 * t * t;
            t = av.x + b2.x; acc.x += f2 * t * t;
            t = av.y + b2.y; acc.y += f2 * t * t;
            t = av.z + b2.z; acc.z += f2 * t * t;
            t = av.w + b2.w; acc.w += f2 * t * t;
            t = av.x + b3.x; acc.x += f3 * t * t;
            t = av.y + b3.y; acc.y += f3 * t * t;
            t = av.z + b3.z; acc.z += f3 * t * t;
            t = av.w + b3.w; acc.w += f3 * t * t;
        }
    }
    acc.x += __shfl_xor(acc.x, 16); acc.y += __shfl_xor(acc.y, 16);
    acc.z += __shfl_xor(acc.z, 16); acc.w += __shfl_xor(acc.w, 16);
    acc.x += __shfl_xor(acc.x, 32); acc.y += __shfl_xor(acc.y, 32);
    acc.z += __shfl_xor(acc.z, 32); acc.w += __shfl_xor(acc.w, 32);
    if (grp == 0) {
        int deg = s1 - s0;
        float inv = 1.f / (float)max(deg, 1);
        float4 r = make_float4(tanhf(acc.x * inv), tanhf(acc.y * inv),
                               tanhf(acc.z * inv), tanhf(acc.w * inv));
        ((float4*)out)[(size_t)node * 16 + col] = r;
    }
}

// ---------------------------------------------------------------------------
extern "C" void kernel_launch(void* const* d_in, const int* in_sizes, int n_in,
                              void* d_out, int out_size, void* d_ws, size_t ws_size,
                              hipStream_t stream) {
    const float* X      = (const float*)d_in[0];
    const int*   ei     = (const int*)d_in[1];
    const float* Wself  = (const float*)d_in[2];
    const float* Wneigh = (const float*)d_in[3];
    const float* bconv  = (const float*)d_in[4];
    const float* Qw     = (const float*)d_in[5];
    const float* Qb     = (const float*)d_in[6];

    int N = in_sizes[0] / NHID;
    int E = in_sizes[1] / 2;
    const int* src = ei;        // edge_index[0]
    const int* dst = ei + E;    // edge_index[1]
    int nB = (N + NPB - 1) >> NPB_SHIFT;           // 391 for N=100K
    int nChunks = (E + CHUNK - 1) / CHUNK;         // 391 for E=3.2M

    // ---- workspace layout (~103 MB) ----
    char* ws = (char*)d_ws;
    size_t bufBytes = (size_t)MAXB * CAP * 4;      // 21.0 MB per side
    unsigned int* buf0 = (unsigned int*)(ws);
    unsigned int* buf1 = (unsigned int*)(ws + bufBytes);
    float* aggF = (float*)(ws);                                   // after build
    float* aF   = (float*)(ws + (size_t)N * NHID * 4);
    float* bF   = (float*)(ws + (size_t)2 * N * NHID * 4);
    size_t pos = (size_t)3 * N * NHID * 4;
    if (pos < 2 * bufBytes) pos = 2 * bufBytes;
    pos = (pos + 255) & ~(size_t)255;
    auto alloc = [&](size_t bytes) -> void* {
        void* p = ws + pos;
        pos = (pos + bytes + 255) & ~(size_t)255;
        return p;
    };
    int* csr0   = (int*)alloc((size_t)E * 4);      // by dst
    int* csr1   = (int*)alloc((size_t)E * 4);      // by src
    int* off0   = (int*)alloc((size_t)(N + 1) * 4);
    int* off1   = (int*)alloc((size_t)(N + 1) * 4);
    int* btail0 = (int*)alloc((size_t)MAXB * 4);
    int* btail1 = (int*)alloc((size_t)MAXB * 4);
    int* boff0  = (int*)alloc((size_t)MAXB * 4);
    int* boff1  = (int*)alloc((size_t)MAXB * 4);
    (void)ws_size; (void)n_in; (void)out_size;

    hipMemsetAsync(btail0, 0, (size_t)2 * MAXB * 4, stream);   // btail0+btail1 contiguous

    k_bucketA<<<nChunks, 256, 0, stream>>>(src, dst, buf0, buf1, btail0, btail1, E, nB);
    k_bscan<<<1, 512, 0, stream>>>(btail0, btail1, boff0, boff1, off0, off1, nB, N);
    k_bucket_csr<<<nB * 2, 256, 0, stream>>>(buf0, buf1, btail0, btail1,
                                             boff0, boff1, off0, off1, csr0, csr1, N);
    k_agg<<<(N + 3) / 4, 256, 0, stream>>>(X, off0, csr0, aggF, N);
    k_phaseA<<<(N + 255) / 256, 256, 0, stream>>>(X, aggF, Wself, Wneigh, bconv, aggF, N);
    k_phaseB<<<(N + 255) / 256, 256, 0, stream>>>(aggF, Qw, Qb, aF, bF, N);
    k_final<<<(N + 3) / 4, 256, 0, stream>>>(aF, bF, off1, csr1, (float*)d_out, N);
}